// Round 1
// baseline (11258.322 us; speedup 1.0000x reference)
//
#include <hip/hip_runtime.h>
#include <cstddef>

// Problem constants
#define BB 16384
#define DIMG 2048
#define HH 512
#define VOCAB 200
#define TT 20

__device__ __forceinline__ float dot4(float4 a, float4 b) {
    return a.x*b.x + a.y*b.y + a.z*b.z + a.w*b.w;
}
__device__ __forceinline__ float sigf(float x) { return 1.f / (1.f + __expf(-x)); }

// ---------------------------------------------------------------------------
// Generic fp32 GEMM: C[M,N] = act(A[M,K] @ W[N,K]^T + bias[N])
// BM=128, BN=128, BK=8, 256 threads, 8x8 per-thread micro-tile.
// ACT: 0 = none, 1 = relu
// ---------------------------------------------------------------------------
template<int ACT>
__global__ __launch_bounds__(256) void gemm_nt(
    const float* __restrict__ A, const float* __restrict__ W,
    const float* __restrict__ bias, float* __restrict__ C,
    int M, int N, int K)
{
    __shared__ float As[8][132];  // 132: 16B-aligned rows (528B), breaks pow2 stride
    __shared__ float Ws[8][132];
    const int t  = threadIdx.x;
    const int bm = blockIdx.x, bn = blockIdx.y;
    const int tr = t >> 4, tc = t & 15;
    const int lr = t >> 1, lk = (t & 1) * 4;

    const float* Ap = A + (size_t)(bm * 128 + lr) * K;
    const float* Wp = W + (size_t)(bn * 128 + lr) * K;

    float acc[8][8];
    #pragma unroll
    for (int i = 0; i < 8; ++i)
        #pragma unroll
        for (int j = 0; j < 8; ++j) acc[i][j] = 0.f;

    for (int k0 = 0; k0 < K; k0 += 8) {
        float4 av = *(const float4*)(Ap + k0 + lk);
        float4 wv = *(const float4*)(Wp + k0 + lk);
        As[lk + 0][lr] = av.x; As[lk + 1][lr] = av.y;
        As[lk + 2][lr] = av.z; As[lk + 3][lr] = av.w;
        Ws[lk + 0][lr] = wv.x; Ws[lk + 1][lr] = wv.y;
        Ws[lk + 2][lr] = wv.z; Ws[lk + 3][lr] = wv.w;
        __syncthreads();
        #pragma unroll
        for (int kk = 0; kk < 8; ++kk) {
            float4 a0 = *(float4*)&As[kk][tr * 8];
            float4 a1 = *(float4*)&As[kk][tr * 8 + 4];
            float4 w0 = *(float4*)&Ws[kk][tc * 8];
            float4 w1 = *(float4*)&Ws[kk][tc * 8 + 4];
            float a[8] = {a0.x, a0.y, a0.z, a0.w, a1.x, a1.y, a1.z, a1.w};
            float w[8] = {w0.x, w0.y, w0.z, w0.w, w1.x, w1.y, w1.z, w1.w};
            #pragma unroll
            for (int i = 0; i < 8; ++i)
                #pragma unroll
                for (int j = 0; j < 8; ++j)
                    acc[i][j] += a[i] * w[j];
        }
        __syncthreads();
    }

    const int cb = bn * 128 + tc * 8;
    float4 b0 = *(const float4*)&bias[cb];
    float4 b1 = *(const float4*)&bias[cb + 4];
    float bb_[8] = {b0.x, b0.y, b0.z, b0.w, b1.x, b1.y, b1.z, b1.w};
    #pragma unroll
    for (int i = 0; i < 8; ++i) {
        size_t row = (size_t)(bm * 128 + tr * 8 + i);
        float* Crow = C + row * N + cb;
        float o[8];
        #pragma unroll
        for (int j = 0; j < 8; ++j) {
            float v = acc[i][j] + bb_[j];
            if (ACT == 1) v = fmaxf(v, 0.f);
            o[j] = v;
        }
        *(float4*)(Crow)     = make_float4(o[0], o[1], o[2], o[3]);
        *(float4*)(Crow + 4) = make_float4(o[4], o[5], o[6], o[7]);
    }
}

// ---------------------------------------------------------------------------
// Fused GRU step: computes hg = hx @ whh^T for all 3 gates over one 64-column
// H-tile, applies gate math in the epilogue, writes new hx. hg never hits mem.
// BM=128 rows, BN=64 cols (per gate), BK=8. 256 threads: 8 rows x 4 cols each.
// ---------------------------------------------------------------------------
__global__ __launch_bounds__(256) void gru_step(
    const float* __restrict__ hx, const float* __restrict__ whh,
    const float* __restrict__ bhh, const float* __restrict__ xg,
    float* __restrict__ hout)
{
    __shared__ float As[8][132];
    __shared__ float Ws[3][8][68];
    const int t  = threadIdx.x;
    const int bm = blockIdx.x;   // 128 blocks over M
    const int bn = blockIdx.y;   // 8 blocks over H (64 cols each)
    const int tr = t >> 4, tc = t & 15;
    const int lr = t >> 1, lk = (t & 1) * 4;

    float acc[3][8][4];
    #pragma unroll
    for (int g = 0; g < 3; ++g)
        #pragma unroll
        for (int i = 0; i < 8; ++i)
            #pragma unroll
            for (int j = 0; j < 4; ++j) acc[g][i][j] = 0.f;

    const float* Ap = hx + (size_t)(bm * 128 + lr) * HH;

    for (int k0 = 0; k0 < HH; k0 += 8) {
        float4 av = *(const float4*)(Ap + k0 + lk);
        As[lk + 0][lr] = av.x; As[lk + 1][lr] = av.y;
        As[lk + 2][lr] = av.z; As[lk + 3][lr] = av.w;
        for (int i = t; i < 384; i += 256) {
            int g = i >> 7, idx = i & 127;
            int r = idx >> 1, l2 = (idx & 1) * 4;
            float4 wv = *(const float4*)&whh[(size_t)(g * HH + bn * 64 + r) * HH + k0 + l2];
            Ws[g][l2 + 0][r] = wv.x; Ws[g][l2 + 1][r] = wv.y;
            Ws[g][l2 + 2][r] = wv.z; Ws[g][l2 + 3][r] = wv.w;
        }
        __syncthreads();
        #pragma unroll
        for (int kk = 0; kk < 8; ++kk) {
            float4 a0 = *(float4*)&As[kk][tr * 8];
            float4 a1 = *(float4*)&As[kk][tr * 8 + 4];
            float a[8] = {a0.x, a0.y, a0.z, a0.w, a1.x, a1.y, a1.z, a1.w};
            float4 wr = *(float4*)&Ws[0][kk][tc * 4];
            float4 wz = *(float4*)&Ws[1][kk][tc * 4];
            float4 wn = *(float4*)&Ws[2][kk][tc * 4];
            #pragma unroll
            for (int i = 0; i < 8; ++i) {
                acc[0][i][0] += a[i] * wr.x; acc[0][i][1] += a[i] * wr.y;
                acc[0][i][2] += a[i] * wr.z; acc[0][i][3] += a[i] * wr.w;
                acc[1][i][0] += a[i] * wz.x; acc[1][i][1] += a[i] * wz.y;
                acc[1][i][2] += a[i] * wz.z; acc[1][i][3] += a[i] * wz.w;
                acc[2][i][0] += a[i] * wn.x; acc[2][i][1] += a[i] * wn.y;
                acc[2][i][2] += a[i] * wn.z; acc[2][i][3] += a[i] * wn.w;
            }
        }
        __syncthreads();
    }

    const int colb = bn * 64 + tc * 4;
    float4 br = *(const float4*)&bhh[colb];
    float4 bz = *(const float4*)&bhh[HH + colb];
    float4 bn_ = *(const float4*)&bhh[2 * HH + colb];

    #pragma unroll
    for (int i = 0; i < 8; ++i) {
        size_t row = (size_t)(bm * 128 + tr * 8 + i);
        const float* xrow = xg + row * (3 * HH) + colb;
        float4 xr = *(const float4*)(xrow);
        float4 xz = *(const float4*)(xrow + HH);
        float4 xn = *(const float4*)(xrow + 2 * HH);
        float4 ho = *(const float4*)&hx[row * HH + colb];
        float4 res;
        {
            float r = sigf(xr.x + acc[0][i][0] + br.x);
            float z = sigf(xz.x + acc[1][i][0] + bz.x);
            float n = tanhf(xn.x + r * (acc[2][i][0] + bn_.x));
            res.x = (1.f - z) * n + z * ho.x;
        }
        {
            float r = sigf(xr.y + acc[0][i][1] + br.y);
            float z = sigf(xz.y + acc[1][i][1] + bz.y);
            float n = tanhf(xn.y + r * (acc[2][i][1] + bn_.y));
            res.y = (1.f - z) * n + z * ho.y;
        }
        {
            float r = sigf(xr.z + acc[0][i][2] + br.z);
            float z = sigf(xz.z + acc[1][i][2] + bz.z);
            float n = tanhf(xn.z + r * (acc[2][i][2] + bn_.z));
            res.z = (1.f - z) * n + z * ho.z;
        }
        {
            float r = sigf(xr.w + acc[0][i][3] + br.w);
            float z = sigf(xz.w + acc[1][i][3] + bz.w);
            float n = tanhf(xn.w + r * (acc[2][i][3] + bn_.w));
            res.w = (1.f - z) * n + z * ho.w;
        }
        *(float4*)&hout[row * HH + colb] = res;
    }
}

// ---------------------------------------------------------------------------
// Fused actor+critic heads for one timestep. Block = 32 batch rows.
//  phase1: a1 = tanh(hx@aw1^T+ab1), c1 = tanh(hx@cw1^T+cb1)   (K=512, LDS-tiled)
//  phase2a: a2 = tanh(a1@aw2^T+ab2), c2 = tanh(c1@cw2^T+cb2)  (K=64)
//  phase2b: logits = a2@aw3^T+ab3 -> log-softmax stats, lp gather, entropy
//  phase2c: v = c2 . cw3 + cb3
// ---------------------------------------------------------------------------
__global__ __launch_bounds__(256) void heads_kernel(
    const float* __restrict__ hx,
    const float* __restrict__ aw1, const float* __restrict__ ab1,
    const float* __restrict__ aw2, const float* __restrict__ ab2,
    const float* __restrict__ aw3, const float* __restrict__ ab3,
    const float* __restrict__ cw1, const float* __restrict__ cb1,
    const float* __restrict__ cw2, const float* __restrict__ cb2,
    const float* __restrict__ cw3, const float* __restrict__ cb3,
    const int* __restrict__ actions,
    float* __restrict__ out_lp, float* __restrict__ out_ent,
    float* __restrict__ out_v, int tstep)
{
    __shared__ float sA[32 * 68];    // hx tile -> later a1
    __shared__ float sW1[64 * 68];   // aw1 tile -> later c1 (rows 0..31)
    __shared__ float sW2[64 * 68];   // cw1 tile -> later a2 (rows 0..31), c2 (32..63)
    const int t = threadIdx.x;
    const int row0 = blockIdx.x * 32;
    const int pr = (t >> 4) * 2;    // 2 rows per thread
    const int pc = (t & 15) * 4;    // 4 cols per thread

    float aA[2][4] = {{0,0,0,0},{0,0,0,0}};
    float aC[2][4] = {{0,0,0,0},{0,0,0,0}};

    for (int k0 = 0; k0 < HH; k0 += 64) {
        for (int i = t; i < 512; i += 256) {
            int r = i >> 4, l = (i & 15) * 4;
            *(float4*)&sA[r * 68 + l] = *(const float4*)&hx[(size_t)(row0 + r) * HH + k0 + l];
        }
        for (int i = t; i < 1024; i += 256) {
            int r = i >> 4, l = (i & 15) * 4;
            *(float4*)&sW1[r * 68 + l] = *(const float4*)&aw1[(size_t)r * HH + k0 + l];
            *(float4*)&sW2[r * 68 + l] = *(const float4*)&cw1[(size_t)r * HH + k0 + l];
        }
        __syncthreads();
        #pragma unroll 4
        for (int kk = 0; kk < 64; kk += 4) {
            float4 h0 = *(float4*)&sA[pr * 68 + kk];
            float4 h1 = *(float4*)&sA[(pr + 1) * 68 + kk];
            #pragma unroll
            for (int c = 0; c < 4; ++c) {
                float4 wa = *(float4*)&sW1[(pc + c) * 68 + kk];
                float4 wc = *(float4*)&sW2[(pc + c) * 68 + kk];
                aA[0][c] += dot4(h0, wa); aA[1][c] += dot4(h1, wa);
                aC[0][c] += dot4(h0, wc); aC[1][c] += dot4(h1, wc);
            }
        }
        __syncthreads();
    }

    // a1 -> sA rows 0..31 ; c1 -> sW1 rows 0..31
    #pragma unroll
    for (int rr = 0; rr < 2; ++rr)
        #pragma unroll
        for (int c = 0; c < 4; ++c) {
            sA[(pr + rr) * 68 + pc + c]  = tanhf(aA[rr][c] + ab1[pc + c]);
            sW1[(pr + rr) * 68 + pc + c] = tanhf(aC[rr][c] + cb1[pc + c]);
        }
    __syncthreads();

    // phase 2a: a2, c2 (K=64), weights straight from global (L1/L2 resident)
    float bA[2][4] = {{0,0,0,0},{0,0,0,0}};
    float bC[2][4] = {{0,0,0,0},{0,0,0,0}};
    #pragma unroll 4
    for (int kk = 0; kk < 64; kk += 4) {
        float4 a0  = *(float4*)&sA[pr * 68 + kk];
        float4 a1v = *(float4*)&sA[(pr + 1) * 68 + kk];
        float4 c0  = *(float4*)&sW1[pr * 68 + kk];
        float4 c1v = *(float4*)&sW1[(pr + 1) * 68 + kk];
        #pragma unroll
        for (int c = 0; c < 4; ++c) {
            float4 w2a = *(const float4*)&aw2[(size_t)(pc + c) * 64 + kk];
            float4 w2c = *(const float4*)&cw2[(size_t)(pc + c) * 64 + kk];
            bA[0][c] += dot4(a0, w2a); bA[1][c] += dot4(a1v, w2a);
            bC[0][c] += dot4(c0, w2c); bC[1][c] += dot4(c1v, w2c);
        }
    }
    __syncthreads();
    // a2 -> sW2 rows 0..31 ; c2 -> sW2 rows 32..63
    #pragma unroll
    for (int rr = 0; rr < 2; ++rr)
        #pragma unroll
        for (int c = 0; c < 4; ++c) {
            sW2[(pr + rr) * 68 + pc + c]        = tanhf(bA[rr][c] + ab2[pc + c]);
            sW2[(32 + pr + rr) * 68 + pc + c]   = tanhf(bC[rr][c] + cb2[pc + c]);
        }
    __syncthreads();

    // phase 2b: logits + log-softmax stats. 8 threads per row; 25 cols each.
    const int lr = t >> 3, lj = t & 7;
    float lg[25];
    #pragma unroll
    for (int m = 0; m < 25; ++m) lg[m] = ab3[m * 8 + lj];
    for (int kk = 0; kk < 64; kk += 4) {
        float4 a4 = *(float4*)&sW2[lr * 68 + kk];
        #pragma unroll
        for (int m = 0; m < 25; ++m) {
            float4 w4 = *(const float4*)&aw3[(size_t)(m * 8 + lj) * 64 + kk];
            lg[m] += dot4(a4, w4);
        }
    }
    float mx = lg[0];
    #pragma unroll
    for (int m = 1; m < 25; ++m) mx = fmaxf(mx, lg[m]);
    #pragma unroll
    for (int o = 1; o < 8; o <<= 1) mx = fmaxf(mx, __shfl_xor(mx, o));
    float s1 = 0.f, s2 = 0.f;
    #pragma unroll
    for (int m = 0; m < 25; ++m) {
        float e = __expf(lg[m] - mx);
        s1 += e; s2 += e * lg[m];
    }
    #pragma unroll
    for (int o = 1; o < 8; o <<= 1) { s1 += __shfl_xor(s1, o); s2 += __shfl_xor(s2, o); }
    float lse = mx + __logf(s1);
    float ent = lse - s2 / s1;

    const int gr = row0 + lr;
    const int act = actions[(size_t)gr * TT + tstep];
    float sel = 0.f;
    #pragma unroll
    for (int m = 0; m < 25; ++m) sel = (m * 8 + lj == act) ? lg[m] : sel;
    if ((act & 7) == lj) out_lp[(size_t)gr * TT + tstep] = sel - lse;
    if (lj == 0)         out_ent[(size_t)gr * TT + tstep] = ent;

    // phase 2c: value. 8 threads per row, 8 k each, shuffle-reduce.
    float pv;
    {
        int k = lj * 8;
        float4 c4a = *(float4*)&sW2[(32 + lr) * 68 + k];
        float4 c4b = *(float4*)&sW2[(32 + lr) * 68 + k + 4];
        float4 w4a = *(const float4*)&cw3[k];
        float4 w4b = *(const float4*)&cw3[k + 4];
        pv = dot4(c4a, w4a) + dot4(c4b, w4b);
    }
    #pragma unroll
    for (int o = 1; o < 8; o <<= 1) pv += __shfl_xor(pv, o);
    if (lj == 0) out_v[(size_t)gr * TT + tstep] = pv + cb3[0];
}

__global__ void zero_kernel(float4* __restrict__ p) {
    p[(size_t)blockIdx.x * 256 + threadIdx.x] = make_float4(0.f, 0.f, 0.f, 0.f);
}

__global__ void copy_actions(const int* __restrict__ a, float* __restrict__ o, int n) {
    int i = blockIdx.x * 256 + threadIdx.x;
    if (i < n) o[i] = (float)a[i];
}

extern "C" void kernel_launch(void* const* d_in, const int* in_sizes, int n_in,
                              void* d_out, int out_size, void* d_ws, size_t ws_size,
                              hipStream_t stream)
{
    const float* images = (const float*)d_in[0];
    const int*   actions = (const int*)d_in[1];
    const float* enc_w1 = (const float*)d_in[2];
    const float* enc_b1 = (const float*)d_in[3];
    const float* enc_w2 = (const float*)d_in[4];
    const float* enc_b2 = (const float*)d_in[5];
    const float* gru_wih = (const float*)d_in[6];
    const float* gru_bih = (const float*)d_in[7];
    const float* gru_whh = (const float*)d_in[8];
    const float* gru_bhh = (const float*)d_in[9];
    const float* act_w1 = (const float*)d_in[10];
    const float* act_b1 = (const float*)d_in[11];
    const float* act_w2 = (const float*)d_in[12];
    const float* act_b2 = (const float*)d_in[13];
    const float* act_w3 = (const float*)d_in[14];
    const float* act_b3 = (const float*)d_in[15];
    const float* cri_w1 = (const float*)d_in[16];
    const float* cri_b1 = (const float*)d_in[17];
    const float* cri_w2 = (const float*)d_in[18];
    const float* cri_b2 = (const float*)d_in[19];
    const float* cri_w3 = (const float*)d_in[20];
    const float* cri_b3 = (const float*)d_in[21];

    float* ws   = (float*)d_ws;
    float* buf1 = ws;                                  // [B,H]
    float* buf2 = buf1 + (size_t)BB * HH;              // [B,H]
    float* xg   = buf2 + (size_t)BB * HH;              // [B,3H]

    float* out_act = (float*)d_out;
    float* out_lp  = out_act + (size_t)BB * TT;
    float* out_ent = out_lp  + (size_t)BB * TT;
    float* out_v   = out_ent + (size_t)BB * TT;

    dim3 blk(256);

    // encoder: buf1 = relu(images@enc_w1^T+b1); buf2 = buf1@enc_w2^T+b2 (= x)
    gemm_nt<1><<<dim3(BB / 128, 512 / 128), blk, 0, stream>>>(images, enc_w1, enc_b1, buf1, BB, 512, DIMG);
    gemm_nt<0><<<dim3(BB / 128, 512 / 128), blk, 0, stream>>>(buf1, enc_w2, enc_b2, buf2, BB, 512, HH);
    // xg = x@gru_wih^T + bih  [B, 3H]
    gemm_nt<0><<<dim3(BB / 128, 1536 / 128), blk, 0, stream>>>(buf2, gru_wih, gru_bih, xg, BB, 1536, HH);

    // hx0 = 0 in buf1 (buf1's encoder contents already consumed)
    zero_kernel<<<((size_t)BB * HH / 4) / 256, blk, 0, stream>>>((float4*)buf1);
    copy_actions<<<(BB * TT + 255) / 256, blk, 0, stream>>>(actions, out_act, BB * TT);

    for (int t = 0; t < TT; ++t) {
        const float* hin = (t & 1) ? buf2 : buf1;
        float*       hout = (t & 1) ? buf1 : buf2;
        gru_step<<<dim3(BB / 128, HH / 64), blk, 0, stream>>>(hin, gru_whh, gru_bhh, xg, hout);
        heads_kernel<<<dim3(BB / 32), blk, 0, stream>>>(hout,
            act_w1, act_b1, act_w2, act_b2, act_w3, act_b3,
            cri_w1, cri_b1, cri_w2, cri_b2, cri_w3, cri_b3,
            actions, out_lp, out_ent, out_v, t);
    }
}

// Round 2
// 5386.740 us; speedup vs baseline: 2.0900x; 2.0900x over previous
//
#include <hip/hip_runtime.h>
#include <cstddef>
#include <cstdint>

#define BB 16384
#define DIMG 2048
#define HH 512
#define VOCAB 200
#define TT 20

using frag16 = __attribute__((ext_vector_type(8))) short;   // 8 x bf16 (4 VGPRs)
using f32x4v = __attribute__((ext_vector_type(4))) float;   // MFMA accumulator

__device__ __forceinline__ float bf2f(unsigned short u) {
    union { unsigned int i; float f; } c; c.i = ((unsigned int)u) << 16; return c.f;
}
__device__ __forceinline__ unsigned short f2bf(float f) {
    union { float f; unsigned int i; } c; c.f = f;
    unsigned int u = c.i;
    u = (u + 0x7FFFu + ((u >> 16) & 1u)) >> 16;   // RTNE
    return (unsigned short)u;
}
__device__ __forceinline__ float sigf(float x) { return 1.f / (1.f + __expf(-x)); }
__device__ __forceinline__ float dot4(float4 a, float4 b) {
    return a.x*b.x + a.y*b.y + a.z*b.z + a.w*b.w;
}
// async global->LDS, 16B per lane; lds dest = wave-uniform base + lane*16
__device__ __forceinline__ void gload16(const void* g, void* l) {
    __builtin_amdgcn_global_load_lds(
        (__attribute__((address_space(1))) void*)g,
        (__attribute__((address_space(3))) void*)l, 16, 0, 0);
}

// ---------------------------------------------------------------------------
// bf16 MFMA GEMM: C[M,N] = act(A[M,K] @ W[N,K]^T + bias)  (both K-contiguous)
// 128x128 tile, BK=32, 4 waves each 64x64 (4x4 16x16 MFMA tiles).
// OUTBF: 1 -> bf16 out (Cb), 0 -> fp32 out (Cf). ACT: 1 -> relu.
// ---------------------------------------------------------------------------
template<int ACT, int OUTBF>
__global__ __launch_bounds__(256) void gemm_bt_mfma(
    const unsigned short* __restrict__ A, const unsigned short* __restrict__ W,
    const float* __restrict__ bias, float* __restrict__ Cf,
    unsigned short* __restrict__ Cb, int M, int N, int K)
{
    __shared__ unsigned short As[128 * 32];   // [128][32] bf16, row-major, 8KB
    __shared__ unsigned short Ws[128 * 32];
    const int t = threadIdx.x;
    const int lane = t & 63, w = t >> 6;
    const int bm = blockIdx.x, bn = blockIdx.y;
    const int wm = (w >> 1) * 64, wn = (w & 1) * 64;

    f32x4v acc[4][4];
    #pragma unroll
    for (int i = 0; i < 4; ++i)
        #pragma unroll
        for (int j = 0; j < 4; ++j)
            #pragma unroll
            for (int r = 0; r < 4; ++r) acc[i][j][r] = 0.f;

    const unsigned short* Ag  = A + (size_t)(bm * 128 + (t >> 2)) * K + (t & 3) * 8;
    const unsigned short* Ag2 = A + (size_t)(bm * 128 + 64 + (t >> 2)) * K + (t & 3) * 8;
    const unsigned short* Wg  = W + (size_t)(bn * 128 + (t >> 2)) * K + (t & 3) * 8;
    const unsigned short* Wg2 = W + (size_t)(bn * 128 + 64 + (t >> 2)) * K + (t & 3) * 8;
    char* AsB = (char*)As; char* WsB = (char*)Ws;

    const int kIters = K >> 5;
    for (int ki = 0; ki < kIters; ++ki) {
        const int k0 = ki * 32;
        gload16(Ag  + k0, AsB + w * 1024);
        gload16(Ag2 + k0, AsB + 4096 + w * 1024);
        gload16(Wg  + k0, WsB + w * 1024);
        gload16(Wg2 + k0, WsB + 4096 + w * 1024);
        __syncthreads();
        frag16 af[4], bf[4];
        #pragma unroll
        for (int i = 0; i < 4; ++i) {
            af[i] = *(const frag16*)(AsB + (wm + i * 16 + (lane & 15)) * 64 + (lane >> 4) * 16);
            bf[i] = *(const frag16*)(WsB + (wn + i * 16 + (lane & 15)) * 64 + (lane >> 4) * 16);
        }
        #pragma unroll
        for (int i = 0; i < 4; ++i)
            #pragma unroll
            for (int j = 0; j < 4; ++j)
                acc[i][j] = __builtin_amdgcn_mfma_f32_16x16x32_bf16(af[i], bf[j], acc[i][j], 0, 0, 0);
        __syncthreads();
    }

    #pragma unroll
    for (int j = 0; j < 4; ++j) {
        const int gn = bn * 128 + wn + j * 16 + (lane & 15);
        const float bv = bias[gn];
        #pragma unroll
        for (int i = 0; i < 4; ++i) {
            #pragma unroll
            for (int r = 0; r < 4; ++r) {
                const size_t gm = (size_t)(bm * 128 + wm + i * 16 + (lane >> 4) * 4 + r);
                float v = acc[i][j][r] + bv;
                if (ACT == 1) v = fmaxf(v, 0.f);
                if (OUTBF) Cb[gm * N + gn] = f2bf(v);
                else       Cf[gm * N + gn] = v;
            }
        }
    }
}

// ---------------------------------------------------------------------------
// Fused GRU step, bf16 MFMA. Block tile: 128 rows x 64 h-cols x 3 gates.
// 4 waves, wave w owns 32 rows (2x 16-row MFMA tiles) x all 64 cols.
// Epilogue applies gate math; hg never materialized.
// ---------------------------------------------------------------------------
__global__ __launch_bounds__(256) void gru_mfma(
    const unsigned short* __restrict__ hb,    // h_{t-1} bf16 [B,H]
    const unsigned short* __restrict__ whhb,  // [3H,H] bf16
    const float* __restrict__ bhh,            // [3H]
    const float* __restrict__ xg,             // [B,3H] fp32
    unsigned short* __restrict__ hob)         // h_t bf16 [B,H]
{
    __shared__ unsigned short As[128 * 32];    // 8KB
    __shared__ unsigned short Ws[3 * 64 * 32]; // 12KB, [gate][64][32]
    const int t = threadIdx.x;
    const int lane = t & 63, w = t >> 6;
    const int bm = blockIdx.x, bn = blockIdx.y;
    const int wm = w * 32;

    f32x4v acc[3][2][4];
    #pragma unroll
    for (int g = 0; g < 3; ++g)
        #pragma unroll
        for (int i = 0; i < 2; ++i)
            #pragma unroll
            for (int j = 0; j < 4; ++j)
                #pragma unroll
                for (int r = 0; r < 4; ++r) acc[g][i][j][r] = 0.f;

    const unsigned short* Ag  = hb + (size_t)(bm * 128 + (t >> 2)) * HH + (t & 3) * 8;
    const unsigned short* Ag2 = hb + (size_t)(bm * 128 + 64 + (t >> 2)) * HH + (t & 3) * 8;
    const unsigned short* Wg0 = whhb + (size_t)(0 * HH + bn * 64 + (t >> 2)) * HH + (t & 3) * 8;
    const unsigned short* Wg1 = whhb + (size_t)(1 * HH + bn * 64 + (t >> 2)) * HH + (t & 3) * 8;
    const unsigned short* Wg2 = whhb + (size_t)(2 * HH + bn * 64 + (t >> 2)) * HH + (t & 3) * 8;
    char* AsB = (char*)As; char* WsB = (char*)Ws;

    for (int ki = 0; ki < 16; ++ki) {
        const int k0 = ki * 32;
        gload16(Ag  + k0, AsB + w * 1024);
        gload16(Ag2 + k0, AsB + 4096 + w * 1024);
        gload16(Wg0 + k0, WsB + w * 1024);
        gload16(Wg1 + k0, WsB + 4096 + w * 1024);
        gload16(Wg2 + k0, WsB + 8192 + w * 1024);
        __syncthreads();
        frag16 af0 = *(const frag16*)(AsB + (wm + (lane & 15)) * 64 + (lane >> 4) * 16);
        frag16 af1 = *(const frag16*)(AsB + (wm + 16 + (lane & 15)) * 64 + (lane >> 4) * 16);
        #pragma unroll
        for (int g = 0; g < 3; ++g) {
            #pragma unroll
            for (int j = 0; j < 4; ++j) {
                frag16 bf = *(const frag16*)(WsB + g * 4096 + (j * 16 + (lane & 15)) * 64 + (lane >> 4) * 16);
                acc[g][0][j] = __builtin_amdgcn_mfma_f32_16x16x32_bf16(af0, bf, acc[g][0][j], 0, 0, 0);
                acc[g][1][j] = __builtin_amdgcn_mfma_f32_16x16x32_bf16(af1, bf, acc[g][1][j], 0, 0, 0);
            }
        }
        __syncthreads();
    }

    float br[4], bz[4], bnn[4];
    #pragma unroll
    for (int j = 0; j < 4; ++j) {
        const int gc = bn * 64 + j * 16 + (lane & 15);
        br[j] = bhh[gc]; bz[j] = bhh[HH + gc]; bnn[j] = bhh[2 * HH + gc];
    }
    #pragma unroll
    for (int i = 0; i < 2; ++i) {
        #pragma unroll
        for (int r = 0; r < 4; ++r) {
            const size_t gm = (size_t)(bm * 128 + wm + i * 16 + (lane >> 4) * 4 + r);
            const float* xrow = xg + gm * (3 * HH);
            #pragma unroll
            for (int j = 0; j < 4; ++j) {
                const int gc = bn * 64 + j * 16 + (lane & 15);
                const float xr = xrow[gc], xz = xrow[HH + gc], xn = xrow[2 * HH + gc];
                const float hold = bf2f(hb[gm * HH + gc]);
                const float rg = sigf(xr + acc[0][i][j][r] + br[j]);
                const float zg = sigf(xz + acc[1][i][j][r] + bz[j]);
                const float ng = tanhf(xn + rg * (acc[2][i][j][r] + bnn[j]));
                const float h = (1.f - zg) * ng + zg * hold;
                hob[gm * HH + gc] = f2bf(h);
            }
        }
    }
}

// ---------------------------------------------------------------------------
// Fused actor+critic heads (fp32 VALU), reading bf16 h. Unchanged otherwise.
// ---------------------------------------------------------------------------
__global__ __launch_bounds__(256) void heads_kernel(
    const unsigned short* __restrict__ hxb,
    const float* __restrict__ aw1, const float* __restrict__ ab1,
    const float* __restrict__ aw2, const float* __restrict__ ab2,
    const float* __restrict__ aw3, const float* __restrict__ ab3,
    const float* __restrict__ cw1, const float* __restrict__ cb1,
    const float* __restrict__ cw2, const float* __restrict__ cb2,
    const float* __restrict__ cw3, const float* __restrict__ cb3,
    const int* __restrict__ actions,
    float* __restrict__ out_lp, float* __restrict__ out_ent,
    float* __restrict__ out_v, int tstep)
{
    __shared__ float sA[32 * 68];
    __shared__ float sW1[64 * 68];
    __shared__ float sW2[64 * 68];
    const int t = threadIdx.x;
    const int row0 = blockIdx.x * 32;
    const int pr = (t >> 4) * 2;
    const int pc = (t & 15) * 4;

    float aA[2][4] = {{0,0,0,0},{0,0,0,0}};
    float aC[2][4] = {{0,0,0,0},{0,0,0,0}};

    for (int k0 = 0; k0 < HH; k0 += 64) {
        for (int i = t; i < 512; i += 256) {
            int r = i >> 4, l = (i & 15) * 4;
            uint2 uv = *(const uint2*)(hxb + (size_t)(row0 + r) * HH + k0 + l);
            sA[r * 68 + l + 0] = bf2f((unsigned short)(uv.x & 0xFFFF));
            sA[r * 68 + l + 1] = bf2f((unsigned short)(uv.x >> 16));
            sA[r * 68 + l + 2] = bf2f((unsigned short)(uv.y & 0xFFFF));
            sA[r * 68 + l + 3] = bf2f((unsigned short)(uv.y >> 16));
        }
        for (int i = t; i < 1024; i += 256) {
            int r = i >> 4, l = (i & 15) * 4;
            *(float4*)&sW1[r * 68 + l] = *(const float4*)&aw1[(size_t)r * HH + k0 + l];
            *(float4*)&sW2[r * 68 + l] = *(const float4*)&cw1[(size_t)r * HH + k0 + l];
        }
        __syncthreads();
        #pragma unroll 4
        for (int kk = 0; kk < 64; kk += 4) {
            float4 h0 = *(float4*)&sA[pr * 68 + kk];
            float4 h1 = *(float4*)&sA[(pr + 1) * 68 + kk];
            #pragma unroll
            for (int c = 0; c < 4; ++c) {
                float4 wa = *(float4*)&sW1[(pc + c) * 68 + kk];
                float4 wc = *(float4*)&sW2[(pc + c) * 68 + kk];
                aA[0][c] += dot4(h0, wa); aA[1][c] += dot4(h1, wa);
                aC[0][c] += dot4(h0, wc); aC[1][c] += dot4(h1, wc);
            }
        }
        __syncthreads();
    }

    #pragma unroll
    for (int rr = 0; rr < 2; ++rr)
        #pragma unroll
        for (int c = 0; c < 4; ++c) {
            sA[(pr + rr) * 68 + pc + c]  = tanhf(aA[rr][c] + ab1[pc + c]);
            sW1[(pr + rr) * 68 + pc + c] = tanhf(aC[rr][c] + cb1[pc + c]);
        }
    __syncthreads();

    float bA[2][4] = {{0,0,0,0},{0,0,0,0}};
    float bC[2][4] = {{0,0,0,0},{0,0,0,0}};
    #pragma unroll 4
    for (int kk = 0; kk < 64; kk += 4) {
        float4 a0  = *(float4*)&sA[pr * 68 + kk];
        float4 a1v = *(float4*)&sA[(pr + 1) * 68 + kk];
        float4 c0  = *(float4*)&sW1[pr * 68 + kk];
        float4 c1v = *(float4*)&sW1[(pr + 1) * 68 + kk];
        #pragma unroll
        for (int c = 0; c < 4; ++c) {
            float4 w2a = *(const float4*)&aw2[(size_t)(pc + c) * 64 + kk];
            float4 w2c = *(const float4*)&cw2[(size_t)(pc + c) * 64 + kk];
            bA[0][c] += dot4(a0, w2a); bA[1][c] += dot4(a1v, w2a);
            bC[0][c] += dot4(c0, w2c); bC[1][c] += dot4(c1v, w2c);
        }
    }
    __syncthreads();
    #pragma unroll
    for (int rr = 0; rr < 2; ++rr)
        #pragma unroll
        for (int c = 0; c < 4; ++c) {
            sW2[(pr + rr) * 68 + pc + c]      = tanhf(bA[rr][c] + ab2[pc + c]);
            sW2[(32 + pr + rr) * 68 + pc + c] = tanhf(bC[rr][c] + cb2[pc + c]);
        }
    __syncthreads();

    const int lr = t >> 3, lj = t & 7;
    float lg[25];
    #pragma unroll
    for (int m = 0; m < 25; ++m) lg[m] = ab3[m * 8 + lj];
    for (int kk = 0; kk < 64; kk += 4) {
        float4 a4 = *(float4*)&sW2[lr * 68 + kk];
        #pragma unroll
        for (int m = 0; m < 25; ++m) {
            float4 w4 = *(const float4*)&aw3[(size_t)(m * 8 + lj) * 64 + kk];
            lg[m] += dot4(a4, w4);
        }
    }
    float mx = lg[0];
    #pragma unroll
    for (int m = 1; m < 25; ++m) mx = fmaxf(mx, lg[m]);
    #pragma unroll
    for (int o = 1; o < 8; o <<= 1) mx = fmaxf(mx, __shfl_xor(mx, o));
    float s1 = 0.f, s2 = 0.f;
    #pragma unroll
    for (int m = 0; m < 25; ++m) {
        float e = __expf(lg[m] - mx);
        s1 += e; s2 += e * lg[m];
    }
    #pragma unroll
    for (int o = 1; o < 8; o <<= 1) { s1 += __shfl_xor(s1, o); s2 += __shfl_xor(s2, o); }
    float lse = mx + __logf(s1);
    float ent = lse - s2 / s1;

    const int gr = row0 + lr;
    const int act = actions[(size_t)gr * TT + tstep];
    float sel = 0.f;
    #pragma unroll
    for (int m = 0; m < 25; ++m) sel = (m * 8 + lj == act) ? lg[m] : sel;
    if ((act & 7) == lj) out_lp[(size_t)gr * TT + tstep] = sel - lse;
    if (lj == 0)         out_ent[(size_t)gr * TT + tstep] = ent;

    float pv;
    {
        int k = lj * 8;
        float4 c4a = *(float4*)&sW2[(32 + lr) * 68 + k];
        float4 c4b = *(float4*)&sW2[(32 + lr) * 68 + k + 4];
        float4 w4a = *(const float4*)&cw3[k];
        float4 w4b = *(const float4*)&cw3[k + 4];
        pv = dot4(c4a, w4a) + dot4(c4b, w4b);
    }
    #pragma unroll
    for (int o = 1; o < 8; o <<= 1) pv += __shfl_xor(pv, o);
    if (lj == 0) out_v[(size_t)gr * TT + tstep] = pv + cb3[0];
}

__global__ void f2b_kernel(const float* __restrict__ s, unsigned short* __restrict__ d, int n) {
    int i = (blockIdx.x * 256 + threadIdx.x) * 4;
    if (i < n) {
        float4 v = *(const float4*)(s + i);
        ushort4 o;
        o.x = f2bf(v.x); o.y = f2bf(v.y); o.z = f2bf(v.z); o.w = f2bf(v.w);
        *(ushort4*)(d + i) = o;
    }
}

__global__ void zero_kernel(float4* __restrict__ p) {
    p[(size_t)blockIdx.x * 256 + threadIdx.x] = make_float4(0.f, 0.f, 0.f, 0.f);
}

__global__ void copy_actions(const int* __restrict__ a, float* __restrict__ o, int n) {
    int i = blockIdx.x * 256 + threadIdx.x;
    if (i < n) o[i] = (float)a[i];
}

extern "C" void kernel_launch(void* const* d_in, const int* in_sizes, int n_in,
                              void* d_out, int out_size, void* d_ws, size_t ws_size,
                              hipStream_t stream)
{
    const float* images = (const float*)d_in[0];
    const int*   actions = (const int*)d_in[1];
    const float* enc_w1 = (const float*)d_in[2];
    const float* enc_b1 = (const float*)d_in[3];
    const float* enc_w2 = (const float*)d_in[4];
    const float* enc_b2 = (const float*)d_in[5];
    const float* gru_wih = (const float*)d_in[6];
    const float* gru_bih = (const float*)d_in[7];
    const float* gru_whh = (const float*)d_in[8];
    const float* gru_bhh = (const float*)d_in[9];
    const float* act_w1 = (const float*)d_in[10];
    const float* act_b1 = (const float*)d_in[11];
    const float* act_w2 = (const float*)d_in[12];
    const float* act_b2 = (const float*)d_in[13];
    const float* act_w3 = (const float*)d_in[14];
    const float* act_b3 = (const float*)d_in[15];
    const float* cri_w1 = (const float*)d_in[16];
    const float* cri_b1 = (const float*)d_in[17];
    const float* cri_w2 = (const float*)d_in[18];
    const float* cri_b2 = (const float*)d_in[19];
    const float* cri_w3 = (const float*)d_in[20];
    const float* cri_b3 = (const float*)d_in[21];

    char* ws = (char*)d_ws;
    // region 0: xg fp32 [B,3H] = 100663296 B; doubles as images_bf16 (67MB) pre-xg
    float*          xg   = (float*)ws;
    unsigned short* imgb = (unsigned short*)ws;
    unsigned short* hbA  = (unsigned short*)(ws + 100663296);             // 16MB (also y1)
    unsigned short* hbB  = (unsigned short*)(ws + 100663296 + 16777216);  // 16MB (also x)
    unsigned short* w1b  = (unsigned short*)(ws + 134217728);
    unsigned short* w2b  = w1b + 512 * DIMG;
    unsigned short* wihb = w2b + 512 * 512;
    unsigned short* whhb = wihb + 3 * HH * HH;

    float* out_act = (float*)d_out;
    float* out_lp  = out_act + (size_t)BB * TT;
    float* out_ent = out_lp  + (size_t)BB * TT;
    float* out_v   = out_ent + (size_t)BB * TT;

    dim3 blk(256);

    // fp32 -> bf16 conversions
    f2b_kernel<<<(BB * DIMG / 4 + 255) / 256, blk, 0, stream>>>(images, imgb, BB * DIMG);
    f2b_kernel<<<(512 * DIMG / 4 + 255) / 256, blk, 0, stream>>>(enc_w1, w1b, 512 * DIMG);
    f2b_kernel<<<(512 * 512 / 4 + 255) / 256, blk, 0, stream>>>(enc_w2, w2b, 512 * 512);
    f2b_kernel<<<(3 * HH * HH / 4 + 255) / 256, blk, 0, stream>>>(gru_wih, wihb, 3 * HH * HH);
    f2b_kernel<<<(3 * HH * HH / 4 + 255) / 256, blk, 0, stream>>>(gru_whh, whhb, 3 * HH * HH);

    // encoder + input-gate GEMMs (bf16 MFMA)
    gemm_bt_mfma<1, 1><<<dim3(BB / 128, 4), blk, 0, stream>>>(imgb, w1b, enc_b1, nullptr, hbA, BB, 512, DIMG);
    gemm_bt_mfma<0, 1><<<dim3(BB / 128, 4), blk, 0, stream>>>(hbA, w2b, enc_b2, nullptr, hbB, BB, 512, HH);
    gemm_bt_mfma<0, 0><<<dim3(BB / 128, 12), blk, 0, stream>>>(hbB, wihb, gru_bih, xg, nullptr, BB, 1536, HH);

    // h0 = 0 (hbA; its y1 contents are dead after enc2)
    zero_kernel<<<4096, blk, 0, stream>>>((float4*)hbA);
    copy_actions<<<(BB * TT + 255) / 256, blk, 0, stream>>>(actions, out_act, BB * TT);

    for (int t = 0; t < TT; ++t) {
        const unsigned short* hin = (t & 1) ? hbB : hbA;
        unsigned short*      hout = (t & 1) ? hbA : hbB;
        gru_mfma<<<dim3(BB / 128, HH / 64), blk, 0, stream>>>(hin, whhb, gru_bhh, xg, hout);
        heads_kernel<<<dim3(BB / 32), blk, 0, stream>>>(hout,
            act_w1, act_b1, act_w2, act_b2, act_w3, act_b3,
            cri_w1, cri_b1, cri_w2, cri_b2, cri_w3, cri_b3,
            actions, out_lp, out_ent, out_v, t);
    }
}

// Round 3
// 1926.553 us; speedup vs baseline: 5.8438x; 2.7961x over previous
//
#include <hip/hip_runtime.h>
#include <cstddef>
#include <cstdint>

#define BB 16384
#define DIMG 2048
#define HH 512
#define VOCAB 200
#define TT 20

using frag16 = __attribute__((ext_vector_type(8))) short;   // 8 x bf16 (4 VGPRs)
using f32x4v = __attribute__((ext_vector_type(4))) float;   // MFMA accumulator

__device__ __forceinline__ float bf2f(unsigned short u) {
    union { unsigned int i; float f; } c; c.i = ((unsigned int)u) << 16; return c.f;
}
__device__ __forceinline__ unsigned short f2bf(float f) {
    union { float f; unsigned int i; } c; c.f = f;
    unsigned int u = c.i;
    u = (u + 0x7FFFu + ((u >> 16) & 1u)) >> 16;   // RTNE
    return (unsigned short)u;
}
__device__ __forceinline__ float sigf(float x) { return 1.f / (1.f + __expf(-x)); }
__device__ __forceinline__ float ftanh(float x) {
    return 1.f - 2.f / (1.f + __expf(2.f * x));
}
// async global->LDS, 16B per lane; lds dest = wave-uniform base + lane*16
__device__ __forceinline__ void gload16(const void* g, void* l) {
    __builtin_amdgcn_global_load_lds(
        (__attribute__((address_space(1))) void*)g,
        (__attribute__((address_space(3))) void*)l, 16, 0, 0);
}

// ---------------------------------------------------------------------------
// bf16 MFMA GEMM: C[M,N] = act(A[M,K] @ W[N,K]^T + bias)  (both K-contiguous)
// 128x128 tile, BK=32, 4 waves each 64x64 (4x4 16x16 MFMA tiles).
// ---------------------------------------------------------------------------
template<int ACT, int OUTBF>
__global__ __launch_bounds__(256) void gemm_bt_mfma(
    const unsigned short* __restrict__ A, const unsigned short* __restrict__ W,
    const float* __restrict__ bias, float* __restrict__ Cf,
    unsigned short* __restrict__ Cb, int M, int N, int K)
{
    __shared__ unsigned short As[128 * 32];
    __shared__ unsigned short Ws[128 * 32];
    const int t = threadIdx.x;
    const int lane = t & 63, w = t >> 6;
    const int bm = blockIdx.x, bn = blockIdx.y;
    const int wm = (w >> 1) * 64, wn = (w & 1) * 64;

    f32x4v acc[4][4];
    #pragma unroll
    for (int i = 0; i < 4; ++i)
        #pragma unroll
        for (int j = 0; j < 4; ++j)
            #pragma unroll
            for (int r = 0; r < 4; ++r) acc[i][j][r] = 0.f;

    const unsigned short* Ag  = A + (size_t)(bm * 128 + (t >> 2)) * K + (t & 3) * 8;
    const unsigned short* Ag2 = A + (size_t)(bm * 128 + 64 + (t >> 2)) * K + (t & 3) * 8;
    const unsigned short* Wg  = W + (size_t)(bn * 128 + (t >> 2)) * K + (t & 3) * 8;
    const unsigned short* Wg2 = W + (size_t)(bn * 128 + 64 + (t >> 2)) * K + (t & 3) * 8;
    char* AsB = (char*)As; char* WsB = (char*)Ws;

    const int kIters = K >> 5;
    for (int ki = 0; ki < kIters; ++ki) {
        const int k0 = ki * 32;
        gload16(Ag  + k0, AsB + w * 1024);
        gload16(Ag2 + k0, AsB + 4096 + w * 1024);
        gload16(Wg  + k0, WsB + w * 1024);
        gload16(Wg2 + k0, WsB + 4096 + w * 1024);
        __syncthreads();
        frag16 af[4], bf[4];
        #pragma unroll
        for (int i = 0; i < 4; ++i) {
            af[i] = *(const frag16*)(AsB + (wm + i * 16 + (lane & 15)) * 64 + (lane >> 4) * 16);
            bf[i] = *(const frag16*)(WsB + (wn + i * 16 + (lane & 15)) * 64 + (lane >> 4) * 16);
        }
        #pragma unroll
        for (int i = 0; i < 4; ++i)
            #pragma unroll
            for (int j = 0; j < 4; ++j)
                acc[i][j] = __builtin_amdgcn_mfma_f32_16x16x32_bf16(af[i], bf[j], acc[i][j], 0, 0, 0);
        __syncthreads();
    }

    #pragma unroll
    for (int j = 0; j < 4; ++j) {
        const int gn = bn * 128 + wn + j * 16 + (lane & 15);
        const float bv = bias[gn];
        #pragma unroll
        for (int i = 0; i < 4; ++i) {
            #pragma unroll
            for (int r = 0; r < 4; ++r) {
                const size_t gm = (size_t)(bm * 128 + wm + i * 16 + (lane >> 4) * 4 + r);
                float v = acc[i][j][r] + bv;
                if (ACT == 1) v = fmaxf(v, 0.f);
                if (OUTBF) Cb[gm * N + gn] = f2bf(v);
                else       Cf[gm * N + gn] = v;
            }
        }
    }
}

// ---------------------------------------------------------------------------
// Fused GRU step, bf16 MFMA (unchanged from round 2).
// ---------------------------------------------------------------------------
__global__ __launch_bounds__(256) void gru_mfma(
    const unsigned short* __restrict__ hb,
    const unsigned short* __restrict__ whhb,
    const float* __restrict__ bhh,
    const float* __restrict__ xg,
    unsigned short* __restrict__ hob)
{
    __shared__ unsigned short As[128 * 32];
    __shared__ unsigned short Ws[3 * 64 * 32];
    const int t = threadIdx.x;
    const int lane = t & 63, w = t >> 6;
    const int bm = blockIdx.x, bn = blockIdx.y;
    const int wm = w * 32;

    f32x4v acc[3][2][4];
    #pragma unroll
    for (int g = 0; g < 3; ++g)
        #pragma unroll
        for (int i = 0; i < 2; ++i)
            #pragma unroll
            for (int j = 0; j < 4; ++j)
                #pragma unroll
                for (int r = 0; r < 4; ++r) acc[g][i][j][r] = 0.f;

    const unsigned short* Ag  = hb + (size_t)(bm * 128 + (t >> 2)) * HH + (t & 3) * 8;
    const unsigned short* Ag2 = hb + (size_t)(bm * 128 + 64 + (t >> 2)) * HH + (t & 3) * 8;
    const unsigned short* Wg0 = whhb + (size_t)(0 * HH + bn * 64 + (t >> 2)) * HH + (t & 3) * 8;
    const unsigned short* Wg1 = whhb + (size_t)(1 * HH + bn * 64 + (t >> 2)) * HH + (t & 3) * 8;
    const unsigned short* Wg2 = whhb + (size_t)(2 * HH + bn * 64 + (t >> 2)) * HH + (t & 3) * 8;
    char* AsB = (char*)As; char* WsB = (char*)Ws;

    for (int ki = 0; ki < 16; ++ki) {
        const int k0 = ki * 32;
        gload16(Ag  + k0, AsB + w * 1024);
        gload16(Ag2 + k0, AsB + 4096 + w * 1024);
        gload16(Wg0 + k0, WsB + w * 1024);
        gload16(Wg1 + k0, WsB + 4096 + w * 1024);
        gload16(Wg2 + k0, WsB + 8192 + w * 1024);
        __syncthreads();
        frag16 af0 = *(const frag16*)(AsB + (wm + (lane & 15)) * 64 + (lane >> 4) * 16);
        frag16 af1 = *(const frag16*)(AsB + (wm + 16 + (lane & 15)) * 64 + (lane >> 4) * 16);
        #pragma unroll
        for (int g = 0; g < 3; ++g) {
            #pragma unroll
            for (int j = 0; j < 4; ++j) {
                frag16 bf = *(const frag16*)(WsB + g * 4096 + (j * 16 + (lane & 15)) * 64 + (lane >> 4) * 16);
                acc[g][0][j] = __builtin_amdgcn_mfma_f32_16x16x32_bf16(af0, bf, acc[g][0][j], 0, 0, 0);
                acc[g][1][j] = __builtin_amdgcn_mfma_f32_16x16x32_bf16(af1, bf, acc[g][1][j], 0, 0, 0);
            }
        }
        __syncthreads();
    }

    float br[4], bz[4], bnn[4];
    #pragma unroll
    for (int j = 0; j < 4; ++j) {
        const int gc = bn * 64 + j * 16 + (lane & 15);
        br[j] = bhh[gc]; bz[j] = bhh[HH + gc]; bnn[j] = bhh[2 * HH + gc];
    }
    #pragma unroll
    for (int i = 0; i < 2; ++i) {
        #pragma unroll
        for (int r = 0; r < 4; ++r) {
            const size_t gm = (size_t)(bm * 128 + wm + i * 16 + (lane >> 4) * 4 + r);
            const float* xrow = xg + gm * (3 * HH);
            #pragma unroll
            for (int j = 0; j < 4; ++j) {
                const int gc = bn * 64 + j * 16 + (lane & 15);
                const float xr = xrow[gc], xz = xrow[HH + gc], xn = xrow[2 * HH + gc];
                const float hold = bf2f(hb[gm * HH + gc]);
                const float rg = sigf(xr + acc[0][i][j][r] + br[j]);
                const float zg = sigf(xz + acc[1][i][j][r] + bz[j]);
                const float ng = tanhf(xn + rg * (acc[2][i][j][r] + bnn[j]));
                const float h = (1.f - zg) * ng + zg * hold;
                hob[gm * HH + gc] = f2bf(h);
            }
        }
    }
}

// ---------------------------------------------------------------------------
// Fully-fused MFMA heads: block = 64 batch rows, 4 waves, grid 256.
//  p1: u1[64,128] = tanh(h @ w1c^T + b1c)         (K=512, LDS-staged)
//  p2: u2[64,128] = tanh(u1a @ aw2^T | u1c @ cw2^T) (two 64x64x64 via col-half)
//  p3: logits[64,208] = u2a @ w3s^T + b3s -> softmax stats in C-layout
//  value: VALU dot of u2c with cw3
// ---------------------------------------------------------------------------
__global__ __launch_bounds__(256) void heads_mfma(
    const unsigned short* __restrict__ hxb,
    const unsigned short* __restrict__ w1c,   // [128,512] bf16
    const unsigned short* __restrict__ w2s,   // [128,64] bf16 (aw2 rows 0-63, cw2 64-127)
    const unsigned short* __restrict__ w3s,   // [208,64] bf16 (aw3, rows>=200 zero)
    const float* __restrict__ b1c, const float* __restrict__ b2c,
    const float* __restrict__ b3s,
    const float* __restrict__ cw3, const float* __restrict__ cb3,
    const int* __restrict__ actions,
    float* __restrict__ out_lp, float* __restrict__ out_ent,
    float* __restrict__ out_v, int tstep)
{
    __shared__ unsigned short u1[64 * 136];   // 17408 B; first 12288 B alias staging
    unsigned short* stH = u1;                 // [64][32] bf16 = 4 KB
    unsigned short* stW = u1 + 2048;          // [128][32] bf16 = 8 KB
    const int t = threadIdx.x;
    const int lane = t & 63, w = t >> 6;
    const int q = lane >> 4, m = lane & 15;
    const int row0 = blockIdx.x * 64;

    // ---------------- phase 1 ----------------
    const int wm = (w >> 1) * 32, wn = (w & 1) * 64;
    f32x4v acc[2][4];
    #pragma unroll
    for (int i = 0; i < 2; ++i)
        #pragma unroll
        for (int j = 0; j < 4; ++j)
            #pragma unroll
            for (int r = 0; r < 4; ++r) acc[i][j][r] = 0.f;

    const unsigned short* Hg  = hxb + (size_t)(row0 + (t >> 2)) * HH + (t & 3) * 8;
    const unsigned short* Wg  = w1c + (size_t)(t >> 2) * HH + (t & 3) * 8;
    const unsigned short* Wg2 = w1c + (size_t)(64 + (t >> 2)) * HH + (t & 3) * 8;
    char* sHB = (char*)stH; char* sWB = (char*)stW;

    for (int k0 = 0; k0 < HH; k0 += 32) {
        gload16(Hg  + k0, sHB + w * 1024);
        gload16(Wg  + k0, sWB + w * 1024);
        gload16(Wg2 + k0, sWB + 4096 + w * 1024);
        __syncthreads();
        frag16 af[2], bfr[4];
        #pragma unroll
        for (int i = 0; i < 2; ++i)
            af[i] = *(const frag16*)(sHB + (wm + i * 16 + m) * 64 + q * 16);
        #pragma unroll
        for (int j = 0; j < 4; ++j)
            bfr[j] = *(const frag16*)(sWB + (wn + j * 16 + m) * 64 + q * 16);
        #pragma unroll
        for (int i = 0; i < 2; ++i)
            #pragma unroll
            for (int j = 0; j < 4; ++j)
                acc[i][j] = __builtin_amdgcn_mfma_f32_16x16x32_bf16(af[i], bfr[j], acc[i][j], 0, 0, 0);
        __syncthreads();
    }
    // write u1 = tanh(acc + b1c)  (staging region is dead; last barrier passed)
    #pragma unroll
    for (int j = 0; j < 4; ++j) {
        const int col = wn + j * 16 + m;
        const float bv = b1c[col];
        #pragma unroll
        for (int i = 0; i < 2; ++i)
            #pragma unroll
            for (int r = 0; r < 4; ++r)
                u1[(wm + i * 16 + q * 4 + r) * 136 + col] = f2bf(ftanh(acc[i][j][r] + bv));
    }
    __syncthreads();

    // ---------------- phase 2 ----------------
    // wave column-half: wn==0 -> actor (A k 0-63, w2s rows 0-63); wn==64 -> critic
    f32x4v acc2[2][4];
    #pragma unroll
    for (int i = 0; i < 2; ++i)
        #pragma unroll
        for (int j = 0; j < 4; ++j)
            #pragma unroll
            for (int r = 0; r < 4; ++r) acc2[i][j][r] = 0.f;

    #pragma unroll
    for (int kk = 0; kk < 2; ++kk) {
        frag16 af2[2];
        #pragma unroll
        for (int i = 0; i < 2; ++i)
            af2[i] = *(const frag16*)(u1 + (wm + i * 16 + m) * 136 + wn + kk * 32 + q * 8);
        #pragma unroll
        for (int j = 0; j < 4; ++j) {
            frag16 bf2v = *(const frag16*)(w2s + (size_t)(wn + j * 16 + m) * 64 + kk * 32 + q * 8);
            #pragma unroll
            for (int i = 0; i < 2; ++i)
                acc2[i][j] = __builtin_amdgcn_mfma_f32_16x16x32_bf16(af2[i], bf2v, acc2[i][j], 0, 0, 0);
        }
    }
    __syncthreads();   // all phase-2 reads of u1 done
    #pragma unroll
    for (int j = 0; j < 4; ++j) {
        const int col = wn + j * 16 + m;
        const float bv = b2c[col];
        #pragma unroll
        for (int i = 0; i < 2; ++i)
            #pragma unroll
            for (int r = 0; r < 4; ++r)
                u1[(wm + i * 16 + q * 4 + r) * 136 + col] = f2bf(ftanh(acc2[i][j][r] + bv));
    }
    __syncthreads();

    // ---------------- phase 3: logits + softmax stats ----------------
    // wave w owns rows 16w..16w+15; cols = 13 tiles of 16 (208, valid 0..199)
    f32x4v acc3[13];
    #pragma unroll
    for (int j = 0; j < 13; ++j)
        #pragma unroll
        for (int r = 0; r < 4; ++r) acc3[j][r] = 0.f;

    #pragma unroll
    for (int kk = 0; kk < 2; ++kk) {
        frag16 af3 = *(const frag16*)(u1 + (16 * w + m) * 136 + kk * 32 + q * 8);
        #pragma unroll
        for (int j = 0; j < 13; ++j) {
            frag16 bf3 = *(const frag16*)(w3s + (size_t)(j * 16 + m) * 64 + kk * 32 + q * 8);
            acc3[j] = __builtin_amdgcn_mfma_f32_16x16x32_bf16(af3, bf3, acc3[j], 0, 0, 0);
        }
    }

    float bcol[13];
    #pragma unroll
    for (int j = 0; j < 13; ++j) bcol[j] = b3s[j * 16 + m];
    const bool vlast = (m < 8);   // tile 12: cols 192..199 valid

    #pragma unroll
    for (int r = 0; r < 4; ++r) {
        const int gr = row0 + 16 * w + 4 * q + r;
        const int a = actions[(size_t)gr * TT + tstep];
        float lg[13], mx = -1e30f;
        #pragma unroll
        for (int j = 0; j < 13; ++j) {
            float v = acc3[j][r] + bcol[j];
            lg[j] = (j < 12 || vlast) ? v : -1e30f;
            mx = fmaxf(mx, lg[j]);
        }
        #pragma unroll
        for (int o = 1; o < 16; o <<= 1) mx = fmaxf(mx, __shfl_xor(mx, o));
        float s1 = 0.f, s2 = 0.f, sel = 0.f;
        #pragma unroll
        for (int j = 0; j < 13; ++j) {
            float e = __expf(lg[j] - mx);
            s1 += e; s2 += e * lg[j];
            sel += (j * 16 + m == a) ? lg[j] : 0.f;
        }
        #pragma unroll
        for (int o = 1; o < 16; o <<= 1) {
            s1 += __shfl_xor(s1, o); s2 += __shfl_xor(s2, o); sel += __shfl_xor(sel, o);
        }
        const float lse = mx + __logf(s1);
        if (m == 0) {
            out_lp[(size_t)gr * TT + tstep]  = sel - lse;
            out_ent[(size_t)gr * TT + tstep] = lse - s2 / s1;
        }
    }

    // ---------------- value head (VALU) ----------------
    {
        float pv = 0.f;
        const unsigned short* u2row = u1 + (16 * w + m) * 136 + 64 + q * 16;
        #pragma unroll
        for (int kk = 0; kk < 16; ++kk)
            pv += bf2f(u2row[kk]) * cw3[q * 16 + kk];
        pv += __shfl_xor(pv, 16);
        pv += __shfl_xor(pv, 32);
        if (q == 0) out_v[(size_t)(row0 + 16 * w + m) * TT + tstep] = pv + cb3[0];
    }
}

// ---------------------------------------------------------------------------
// One-time packing of head weights/biases.
// ---------------------------------------------------------------------------
__global__ void prep_heads(
    const float* __restrict__ aw1, const float* __restrict__ cw1,
    const float* __restrict__ aw2, const float* __restrict__ cw2,
    const float* __restrict__ aw3,
    const float* __restrict__ ab1, const float* __restrict__ cb1,
    const float* __restrict__ ab2, const float* __restrict__ cb2,
    const float* __restrict__ ab3,
    unsigned short* __restrict__ w1c, unsigned short* __restrict__ w2s,
    unsigned short* __restrict__ w3s,
    float* __restrict__ b1c, float* __restrict__ b2c, float* __restrict__ b3s)
{
    int i = blockIdx.x * 256 + threadIdx.x;
    if (i < 65536) { int r = i >> 9, c = i & 511;
        w1c[i] = f2bf(r < 64 ? aw1[r * 512 + c] : cw1[(r - 64) * 512 + c]); return; }
    i -= 65536;
    if (i < 8192) { int r = i >> 6, c = i & 63;
        w2s[i] = f2bf(r < 64 ? aw2[r * 64 + c] : cw2[(r - 64) * 64 + c]); return; }
    i -= 8192;
    if (i < 13312) { int r = i >> 6, c = i & 63;
        w3s[i] = f2bf(r < 200 ? aw3[r * 64 + c] : 0.f); return; }
    i -= 13312;
    if (i < 128) { b1c[i] = i < 64 ? ab1[i] : cb1[i - 64]; return; }
    i -= 128;
    if (i < 128) { b2c[i] = i < 64 ? ab2[i] : cb2[i - 64]; return; }
    i -= 128;
    if (i < 208) { b3s[i] = i < 200 ? ab3[i] : 0.f; return; }
}

__global__ void f2b_kernel(const float* __restrict__ s, unsigned short* __restrict__ d, int n) {
    int i = (blockIdx.x * 256 + threadIdx.x) * 4;
    if (i < n) {
        float4 v = *(const float4*)(s + i);
        ushort4 o;
        o.x = f2bf(v.x); o.y = f2bf(v.y); o.z = f2bf(v.z); o.w = f2bf(v.w);
        *(ushort4*)(d + i) = o;
    }
}

__global__ void zero_kernel(float4* __restrict__ p) {
    p[(size_t)blockIdx.x * 256 + threadIdx.x] = make_float4(0.f, 0.f, 0.f, 0.f);
}

__global__ void copy_actions(const int* __restrict__ a, float* __restrict__ o, int n) {
    int i = blockIdx.x * 256 + threadIdx.x;
    if (i < n) o[i] = (float)a[i];
}

extern "C" void kernel_launch(void* const* d_in, const int* in_sizes, int n_in,
                              void* d_out, int out_size, void* d_ws, size_t ws_size,
                              hipStream_t stream)
{
    const float* images = (const float*)d_in[0];
    const int*   actions = (const int*)d_in[1];
    const float* enc_w1 = (const float*)d_in[2];
    const float* enc_b1 = (const float*)d_in[3];
    const float* enc_w2 = (const float*)d_in[4];
    const float* enc_b2 = (const float*)d_in[5];
    const float* gru_wih = (const float*)d_in[6];
    const float* gru_bih = (const float*)d_in[7];
    const float* gru_whh = (const float*)d_in[8];
    const float* gru_bhh = (const float*)d_in[9];
    const float* act_w1 = (const float*)d_in[10];
    const float* act_b1 = (const float*)d_in[11];
    const float* act_w2 = (const float*)d_in[12];
    const float* act_b2 = (const float*)d_in[13];
    const float* act_w3 = (const float*)d_in[14];
    const float* act_b3 = (const float*)d_in[15];
    const float* cri_w1 = (const float*)d_in[16];
    const float* cri_b1 = (const float*)d_in[17];
    const float* cri_w2 = (const float*)d_in[18];
    const float* cri_b2 = (const float*)d_in[19];
    const float* cri_w3 = (const float*)d_in[20];
    const float* cri_b3 = (const float*)d_in[21];

    char* ws = (char*)d_ws;
    float*          xg   = (float*)ws;                                    // [B,3H] f32
    unsigned short* imgb = (unsigned short*)ws;                           // aliases xg pre-encoder
    unsigned short* hbA  = (unsigned short*)(ws + 100663296);
    unsigned short* hbB  = (unsigned short*)(ws + 100663296 + 16777216);
    unsigned short* w1b  = (unsigned short*)(ws + 134217728);
    unsigned short* w2b  = w1b + 512 * DIMG;
    unsigned short* wihb = w2b + 512 * 512;
    unsigned short* whhb = wihb + 3 * HH * HH;
    unsigned short* w1c  = whhb + 3 * HH * HH;        // [128,512]
    unsigned short* w2s  = w1c + 128 * 512;           // [128,64]
    unsigned short* w3s  = w2s + 128 * 64;            // [208,64]
    float*          b1c  = (float*)(w3s + 208 * 64);
    float*          b2c  = b1c + 128;
    float*          b3s  = b2c + 128;

    float* out_act = (float*)d_out;
    float* out_lp  = out_act + (size_t)BB * TT;
    float* out_ent = out_lp  + (size_t)BB * TT;
    float* out_v   = out_ent + (size_t)BB * TT;

    dim3 blk(256);

    f2b_kernel<<<(BB * DIMG / 4 + 255) / 256, blk, 0, stream>>>(images, imgb, BB * DIMG);
    f2b_kernel<<<(512 * DIMG / 4 + 255) / 256, blk, 0, stream>>>(enc_w1, w1b, 512 * DIMG);
    f2b_kernel<<<(512 * 512 / 4 + 255) / 256, blk, 0, stream>>>(enc_w2, w2b, 512 * 512);
    f2b_kernel<<<(3 * HH * HH / 4 + 255) / 256, blk, 0, stream>>>(gru_wih, wihb, 3 * HH * HH);
    f2b_kernel<<<(3 * HH * HH / 4 + 255) / 256, blk, 0, stream>>>(gru_whh, whhb, 3 * HH * HH);
    prep_heads<<<(87504 + 255) / 256, blk, 0, stream>>>(
        act_w1, cri_w1, act_w2, cri_w2, act_w3,
        act_b1, cri_b1, act_b2, cri_b2, act_b3,
        w1c, w2s, w3s, b1c, b2c, b3s);

    gemm_bt_mfma<1, 1><<<dim3(BB / 128, 4), blk, 0, stream>>>(imgb, w1b, enc_b1, nullptr, hbA, BB, 512, DIMG);
    gemm_bt_mfma<0, 1><<<dim3(BB / 128, 4), blk, 0, stream>>>(hbA, w2b, enc_b2, nullptr, hbB, BB, 512, HH);
    gemm_bt_mfma<0, 0><<<dim3(BB / 128, 12), blk, 0, stream>>>(hbB, wihb, gru_bih, xg, nullptr, BB, 1536, HH);

    zero_kernel<<<4096, blk, 0, stream>>>((float4*)hbA);
    copy_actions<<<(BB * TT + 255) / 256, blk, 0, stream>>>(actions, out_act, BB * TT);

    for (int t = 0; t < TT; ++t) {
        const unsigned short* hin = (t & 1) ? hbB : hbA;
        unsigned short*      hout = (t & 1) ? hbA : hbB;
        gru_mfma<<<dim3(BB / 128, HH / 64), blk, 0, stream>>>(hin, whhb, gru_bhh, xg, hout);
        heads_mfma<<<dim3(BB / 64), blk, 0, stream>>>(hout,
            w1c, w2s, w3s, b1c, b2c, b3s, cri_w3, cri_b3,
            actions, out_lp, out_ent, out_v, t);
    }
}

// Round 4
// 1787.283 us; speedup vs baseline: 6.2991x; 1.0779x over previous
//
#include <hip/hip_runtime.h>
#include <hip/hip_fp16.h>
#include <cstddef>
#include <cstdint>

#define BB 16384
#define DIMG 2048
#define HH 512
#define VOCAB 200
#define TT 20

using frag16 = __attribute__((ext_vector_type(8))) short;   // 8 x bf16 (4 VGPRs)
using f32x4v = __attribute__((ext_vector_type(4))) float;   // MFMA accumulator

__device__ __forceinline__ float bf2f(unsigned short u) {
    union { unsigned int i; float f; } c; c.i = ((unsigned int)u) << 16; return c.f;
}
__device__ __forceinline__ unsigned short f2bf(float f) {
    union { float f; unsigned int i; } c; c.f = f;
    unsigned int u = c.i;
    u = (u + 0x7FFFu + ((u >> 16) & 1u)) >> 16;   // RTNE
    return (unsigned short)u;
}
__device__ __forceinline__ float sigf(float x) { return 1.f / (1.f + __expf(-x)); }
__device__ __forceinline__ float ftanh(float x) {
    return 1.f - 2.f / (1.f + __expf(2.f * x));
}
// async global->LDS, 16B/lane; LDS dest = wave-uniform base + lane*16
__device__ __forceinline__ void gload16(const void* g, void* l) {
    __builtin_amdgcn_global_load_lds(
        (__attribute__((address_space(1))) void*)g,
        (__attribute__((address_space(3))) void*)l, 16, 0, 0);
}

// ---------------------------------------------------------------------------
// bf16 MFMA GEMM: C = act(A[M,K] @ W[N,K]^T + bias). OM: 0=f32, 1=bf16, 2=f16.
// ---------------------------------------------------------------------------
template<int ACT, int OM>
__global__ __launch_bounds__(256) void gemm_bt_mfma(
    const unsigned short* __restrict__ A, const unsigned short* __restrict__ W,
    const float* __restrict__ bias, void* __restrict__ Cv, int M, int N, int K)
{
    __shared__ unsigned short As[128 * 32];
    __shared__ unsigned short Ws[128 * 32];
    const int t = threadIdx.x;
    const int lane = t & 63, w = t >> 6;
    const int bm = blockIdx.x, bn = blockIdx.y;
    const int wm = (w >> 1) * 64, wn = (w & 1) * 64;

    f32x4v acc[4][4];
    #pragma unroll
    for (int i = 0; i < 4; ++i)
        #pragma unroll
        for (int j = 0; j < 4; ++j)
            #pragma unroll
            for (int r = 0; r < 4; ++r) acc[i][j][r] = 0.f;

    const unsigned short* Ag  = A + (size_t)(bm * 128 + (t >> 2)) * K + (t & 3) * 8;
    const unsigned short* Ag2 = A + (size_t)(bm * 128 + 64 + (t >> 2)) * K + (t & 3) * 8;
    const unsigned short* Wg  = W + (size_t)(bn * 128 + (t >> 2)) * K + (t & 3) * 8;
    const unsigned short* Wg2 = W + (size_t)(bn * 128 + 64 + (t >> 2)) * K + (t & 3) * 8;
    char* AsB = (char*)As; char* WsB = (char*)Ws;

    const int kIters = K >> 5;
    for (int ki = 0; ki < kIters; ++ki) {
        const int k0 = ki * 32;
        gload16(Ag  + k0, AsB + w * 1024);
        gload16(Ag2 + k0, AsB + 4096 + w * 1024);
        gload16(Wg  + k0, WsB + w * 1024);
        gload16(Wg2 + k0, WsB + 4096 + w * 1024);
        __syncthreads();
        frag16 af[4], bf[4];
        #pragma unroll
        for (int i = 0; i < 4; ++i) {
            af[i] = *(const frag16*)(AsB + (wm + i * 16 + (lane & 15)) * 64 + (lane >> 4) * 16);
            bf[i] = *(const frag16*)(WsB + (wn + i * 16 + (lane & 15)) * 64 + (lane >> 4) * 16);
        }
        #pragma unroll
        for (int i = 0; i < 4; ++i)
            #pragma unroll
            for (int j = 0; j < 4; ++j)
                acc[i][j] = __builtin_amdgcn_mfma_f32_16x16x32_bf16(af[i], bf[j], acc[i][j], 0, 0, 0);
        __syncthreads();
    }

    #pragma unroll
    for (int j = 0; j < 4; ++j) {
        const int gn = bn * 128 + wn + j * 16 + (lane & 15);
        const float bv = bias[gn];
        #pragma unroll
        for (int i = 0; i < 4; ++i) {
            #pragma unroll
            for (int r = 0; r < 4; ++r) {
                const size_t gm = (size_t)(bm * 128 + wm + i * 16 + (lane >> 4) * 4 + r);
                float v = acc[i][j][r] + bv;
                if (ACT == 1) v = fmaxf(v, 0.f);
                if (OM == 0)      ((float*)Cv)[gm * N + gn] = v;
                else if (OM == 1) ((unsigned short*)Cv)[gm * N + gn] = f2bf(v);
                else              ((__half*)Cv)[gm * N + gn] = __float2half(v);
            }
        }
    }
}

// ---------------------------------------------------------------------------
// GRU step body, BK=64, kk-half-split LDS layout. Block: 128 rows x 64 h-cols.
// ---------------------------------------------------------------------------
__device__ __forceinline__ void gru_body(
    unsigned short* lds,
    const unsigned short* __restrict__ hb, unsigned short* __restrict__ hob,
    const unsigned short* __restrict__ whhb, const float* __restrict__ bhh,
    const __half* __restrict__ xg, int bm, int bn, int t)
{
    char* AsB = (char*)lds;            // 16 KB: two 8 KB kk-halves [128][64B]
    char* WsB = (char*)lds + 16384;    // 24 KB: two 12 KB kk-halves [192][64B]
    const int lane = t & 63, w = t >> 6;
    const int q = lane >> 4, m = lane & 15;
    const int wm = w * 32;

    f32x4v acc[3][2][4];
    #pragma unroll
    for (int g = 0; g < 3; ++g)
        #pragma unroll
        for (int i = 0; i < 2; ++i)
            #pragma unroll
            for (int j = 0; j < 4; ++j)
                #pragma unroll
                for (int r = 0; r < 4; ++r) acc[g][i][j][r] = 0.f;

    const int rsub = t >> 2;          // 0..63
    const int ksub = (t & 3) * 8;     // 0..24 within 32-K half
    const unsigned short* Arow[4]; int AldsOff[4];
    #pragma unroll
    for (int c = 0; c < 4; ++c) {
        const int kk = c & 1, rb = (c >> 1) * 64;
        Arow[c] = hb + (size_t)(bm * 128 + rb + rsub) * HH + kk * 32 + ksub;
        AldsOff[c] = kk * 8192 + rb * 64;
    }
    const unsigned short* Wrow[6]; int WldsOff[6];
    #pragma unroll
    for (int c = 0; c < 6; ++c) {
        const int kk = c & 1, rb = (c >> 1) * 64;
        const int p = rb + rsub;                 // packed row 0..191
        const int g = p >> 6, r = p & 63;
        Wrow[c] = whhb + (size_t)(g * HH + bn * 64 + r) * HH + kk * 32 + ksub;
        WldsOff[c] = kk * 12288 + rb * 64;
    }

    for (int ki = 0; ki < 8; ++ki) {
        const int k0 = ki * 64;
        #pragma unroll
        for (int c = 0; c < 4; ++c)
            gload16(Arow[c] + k0, AsB + AldsOff[c] + w * 1024);
        #pragma unroll
        for (int c = 0; c < 6; ++c)
            gload16(Wrow[c] + k0, WsB + WldsOff[c] + w * 1024);
        __syncthreads();
        #pragma unroll
        for (int kk = 0; kk < 2; ++kk) {
            frag16 af0 = *(const frag16*)(AsB + kk * 8192 + (wm + m) * 64 + q * 16);
            frag16 af1 = *(const frag16*)(AsB + kk * 8192 + (wm + 16 + m) * 64 + q * 16);
            #pragma unroll
            for (int g = 0; g < 3; ++g)
                #pragma unroll
                for (int j = 0; j < 4; ++j) {
                    frag16 bf = *(const frag16*)(WsB + kk * 12288 + (g * 64 + j * 16 + m) * 64 + q * 16);
                    acc[g][0][j] = __builtin_amdgcn_mfma_f32_16x16x32_bf16(af0, bf, acc[g][0][j], 0, 0, 0);
                    acc[g][1][j] = __builtin_amdgcn_mfma_f32_16x16x32_bf16(af1, bf, acc[g][1][j], 0, 0, 0);
                }
        }
        __syncthreads();
    }

    float br[4], bz[4], bnn[4];
    #pragma unroll
    for (int j = 0; j < 4; ++j) {
        const int gc = bn * 64 + j * 16 + m;
        br[j] = bhh[gc]; bz[j] = bhh[HH + gc]; bnn[j] = bhh[2 * HH + gc];
    }
    #pragma unroll
    for (int i = 0; i < 2; ++i) {
        #pragma unroll
        for (int r = 0; r < 4; ++r) {
            const size_t gm = (size_t)(bm * 128 + wm + i * 16 + q * 4 + r);
            const __half* xrow = xg + gm * (3 * HH);
            const unsigned short* hrow = hb + gm * HH;
            unsigned short* horow = hob + gm * HH;
            #pragma unroll
            for (int j = 0; j < 4; ++j) {
                const int gc = bn * 64 + j * 16 + m;
                const float xr = __half2float(xrow[gc]);
                const float xz = __half2float(xrow[HH + gc]);
                const float xn = __half2float(xrow[2 * HH + gc]);
                const float hold = bf2f(hrow[gc]);
                const float rg = sigf(xr + acc[0][i][j][r] + br[j]);
                const float zg = sigf(xz + acc[1][i][j][r] + bz[j]);
                const float ng = tanhf(xn + rg * (acc[2][i][j][r] + bnn[j]));
                horow[gc] = f2bf((1.f - zg) * ng + zg * hold);
            }
        }
    }
}

// ---------------------------------------------------------------------------
// Heads body: 32 batch rows per block, BK=64 phase-1 staging (kk-half split).
// ---------------------------------------------------------------------------
__device__ __forceinline__ void heads_body(
    unsigned short* lds, const unsigned short* __restrict__ hxb,
    const unsigned short* __restrict__ w1c, const unsigned short* __restrict__ w2s,
    const unsigned short* __restrict__ w3s,
    const float* __restrict__ b1c, const float* __restrict__ b2c,
    const float* __restrict__ b3s,
    const float* __restrict__ cw3, const float* __restrict__ cb3,
    const int* __restrict__ actions,
    float* __restrict__ out_lp, float* __restrict__ out_ent,
    float* __restrict__ out_v, int tstep, int hblk, int t)
{
    char* sH = (char*)lds;              // 4 KB: two 2 KB kk-halves [32][64B]
    char* sW = (char*)lds + 4096;       // 16 KB: two 8 KB kk-halves [128][64B]
    unsigned short* u1 = lds;           // aliased after phase 1: [32][136]
    const int lane = t & 63, w = t >> 6;
    const int q = lane >> 4, m = lane & 15;
    const int row0 = hblk * 32;
    const int ri = (w & 1) * 16, ch = (w >> 1) * 64;

    // ---------------- phase 1: u1 = tanh(h @ w1c^T + b1c) ----------------
    f32x4v acc[4];
    #pragma unroll
    for (int j = 0; j < 4; ++j)
        #pragma unroll
        for (int r = 0; r < 4; ++r) acc[j][r] = 0.f;

    // stH single call covers both halves: t>>7 = kk, (t>>2)&31 = row
    const unsigned short* Hrow = hxb + (size_t)(row0 + ((t >> 2) & 31)) * HH
                                 + (t >> 7) * 32 + (t & 3) * 8;
    const unsigned short* Wrow[4]; int WldsOff[4];
    #pragma unroll
    for (int c = 0; c < 4; ++c) {
        const int kk = c & 1, rb = (c >> 1) * 64;
        Wrow[c] = w1c + (size_t)(rb + (t >> 2)) * HH + kk * 32 + (t & 3) * 8;
        WldsOff[c] = kk * 8192 + rb * 64;
    }

    for (int ki = 0; ki < 8; ++ki) {
        const int k0 = ki * 64;
        gload16(Hrow + k0, sH + w * 1024);
        #pragma unroll
        for (int c = 0; c < 4; ++c)
            gload16(Wrow[c] + k0, sW + WldsOff[c] + w * 1024);
        __syncthreads();
        #pragma unroll
        for (int kk = 0; kk < 2; ++kk) {
            frag16 af = *(const frag16*)(sH + kk * 2048 + (ri + m) * 64 + q * 16);
            #pragma unroll
            for (int j = 0; j < 4; ++j) {
                frag16 bf = *(const frag16*)(sW + kk * 8192 + (ch + j * 16 + m) * 64 + q * 16);
                acc[j] = __builtin_amdgcn_mfma_f32_16x16x32_bf16(af, bf, acc[j], 0, 0, 0);
            }
        }
        __syncthreads();
    }
    #pragma unroll
    for (int j = 0; j < 4; ++j) {
        const int col = ch + j * 16 + m;
        const float bv = b1c[col];
        #pragma unroll
        for (int r = 0; r < 4; ++r)
            u1[(ri + q * 4 + r) * 136 + col] = f2bf(ftanh(acc[j][r] + bv));
    }
    __syncthreads();

    // ---------------- phase 2: u2 (actor ch=0 / critic ch=64) ----------------
    f32x4v acc2[4];
    #pragma unroll
    for (int j = 0; j < 4; ++j)
        #pragma unroll
        for (int r = 0; r < 4; ++r) acc2[j][r] = 0.f;
    #pragma unroll
    for (int kk = 0; kk < 2; ++kk) {
        frag16 af2 = *(const frag16*)(u1 + (ri + m) * 136 + ch + kk * 32 + q * 8);
        #pragma unroll
        for (int j = 0; j < 4; ++j) {
            frag16 bf2 = *(const frag16*)(w2s + (size_t)(ch + j * 16 + m) * 64 + kk * 32 + q * 8);
            acc2[j] = __builtin_amdgcn_mfma_f32_16x16x32_bf16(af2, bf2, acc2[j], 0, 0, 0);
        }
    }
    __syncthreads();
    #pragma unroll
    for (int j = 0; j < 4; ++j) {
        const int col = ch + j * 16 + m;
        const float bv = b2c[col];
        #pragma unroll
        for (int r = 0; r < 4; ++r)
            u1[(ri + q * 4 + r) * 136 + col] = f2bf(ftanh(acc2[j][r] + bv));
    }
    __syncthreads();

    // ---------------- phase 3 ----------------
    if (w < 2) {
        // logits for rows w*16 .. w*16+15
        f32x4v acc3[13];
        #pragma unroll
        for (int j = 0; j < 13; ++j)
            #pragma unroll
            for (int r = 0; r < 4; ++r) acc3[j][r] = 0.f;
        #pragma unroll
        for (int kk = 0; kk < 2; ++kk) {
            frag16 af3 = *(const frag16*)(u1 + (w * 16 + m) * 136 + kk * 32 + q * 8);
            #pragma unroll
            for (int j = 0; j < 13; ++j) {
                frag16 bf3 = *(const frag16*)(w3s + (size_t)(j * 16 + m) * 64 + kk * 32 + q * 8);
                acc3[j] = __builtin_amdgcn_mfma_f32_16x16x32_bf16(af3, bf3, acc3[j], 0, 0, 0);
            }
        }
        float bcol[13];
        #pragma unroll
        for (int j = 0; j < 13; ++j) bcol[j] = b3s[j * 16 + m];
        const bool vlast = (m < 8);
        #pragma unroll
        for (int r = 0; r < 4; ++r) {
            const int gr = row0 + w * 16 + 4 * q + r;
            const int a = actions[(size_t)gr * TT + tstep];
            float lg[13], mx = -1e30f;
            #pragma unroll
            for (int j = 0; j < 13; ++j) {
                float v = acc3[j][r] + bcol[j];
                lg[j] = (j < 12 || vlast) ? v : -1e30f;
                mx = fmaxf(mx, lg[j]);
            }
            #pragma unroll
            for (int o = 1; o < 16; o <<= 1) mx = fmaxf(mx, __shfl_xor(mx, o));
            float s1 = 0.f, s2 = 0.f, sel = 0.f;
            #pragma unroll
            for (int j = 0; j < 13; ++j) {
                float e = __expf(lg[j] - mx);
                s1 += e; s2 += e * lg[j];
                sel += (j * 16 + m == a) ? lg[j] : 0.f;
            }
            #pragma unroll
            for (int o = 1; o < 16; o <<= 1) {
                s1 += __shfl_xor(s1, o); s2 += __shfl_xor(s2, o); sel += __shfl_xor(sel, o);
            }
            const float lse = mx + __logf(s1);
            if (m == 0) {
                out_lp[(size_t)gr * TT + tstep]  = sel - lse;
                out_ent[(size_t)gr * TT + tstep] = lse - s2 / s1;
            }
        }
    } else {
        // value head: rows (w-2)*16 + m
        const int row = (w - 2) * 16 + m;
        const unsigned short* u2row = u1 + row * 136 + 64 + q * 16;
        float pv = 0.f;
        #pragma unroll
        for (int kk = 0; kk < 16; ++kk)
            pv += bf2f(u2row[kk]) * cw3[q * 16 + kk];
        pv += __shfl_xor(pv, 16);
        pv += __shfl_xor(pv, 32);
        if (q == 0) out_v[(size_t)(row0 + row) * TT + tstep] = pv + cb3[0];
    }
}

// ---------------------------------------------------------------------------
// Fused per-step launch: blocks 0..1023 = gru_t ; blocks 1024..1535 = heads_{t-1}
// (both only read hin; outputs disjoint). hstep = -1 skips heads (t == 0).
// ---------------------------------------------------------------------------
__global__ __launch_bounds__(256) void step_fused(
    const unsigned short* __restrict__ hin, unsigned short* __restrict__ hout,
    const unsigned short* __restrict__ whhb, const float* __restrict__ bhh,
    const __half* __restrict__ xg,
    const unsigned short* __restrict__ w1c, const unsigned short* __restrict__ w2s,
    const unsigned short* __restrict__ w3s,
    const float* __restrict__ b1c, const float* __restrict__ b2c,
    const float* __restrict__ b3s,
    const float* __restrict__ cw3, const float* __restrict__ cb3,
    const int* __restrict__ actions,
    float* __restrict__ out_lp, float* __restrict__ out_ent,
    float* __restrict__ out_v, int hstep)
{
    __shared__ unsigned short lds[20480];   // 40 KB
    const int b = blockIdx.x;
    if (b < 1024) {
        gru_body(lds, hin, hout, whhb, bhh, xg, b >> 3, b & 7, threadIdx.x);
    } else if (hstep >= 0) {
        heads_body(lds, hin, w1c, w2s, w3s, b1c, b2c, b3s, cw3, cb3,
                   actions, out_lp, out_ent, out_v, hstep, b - 1024, threadIdx.x);
    }
}

__global__ __launch_bounds__(256) void heads_tail(
    const unsigned short* __restrict__ hx,
    const unsigned short* __restrict__ w1c, const unsigned short* __restrict__ w2s,
    const unsigned short* __restrict__ w3s,
    const float* __restrict__ b1c, const float* __restrict__ b2c,
    const float* __restrict__ b3s,
    const float* __restrict__ cw3, const float* __restrict__ cb3,
    const int* __restrict__ actions,
    float* __restrict__ out_lp, float* __restrict__ out_ent,
    float* __restrict__ out_v, int tstep)
{
    __shared__ unsigned short lds[10240];   // 20 KB
    heads_body(lds, hx, w1c, w2s, w3s, b1c, b2c, b3s, cw3, cb3,
               actions, out_lp, out_ent, out_v, tstep, blockIdx.x, threadIdx.x);
}

// ---------------------------------------------------------------------------
// One-time packing of head weights/biases.
// ---------------------------------------------------------------------------
__global__ void prep_heads(
    const float* __restrict__ aw1, const float* __restrict__ cw1,
    const float* __restrict__ aw2, const float* __restrict__ cw2,
    const float* __restrict__ aw3,
    const float* __restrict__ ab1, const float* __restrict__ cb1,
    const float* __restrict__ ab2, const float* __restrict__ cb2,
    const float* __restrict__ ab3,
    unsigned short* __restrict__ w1c, unsigned short* __restrict__ w2s,
    unsigned short* __restrict__ w3s,
    float* __restrict__ b1c, float* __restrict__ b2c, float* __restrict__ b3s)
{
    int i = blockIdx.x * 256 + threadIdx.x;
    if (i < 65536) { int r = i >> 9, c = i & 511;
        w1c[i] = f2bf(r < 64 ? aw1[r * 512 + c] : cw1[(r - 64) * 512 + c]); return; }
    i -= 65536;
    if (i < 8192) { int r = i >> 6, c = i & 63;
        w2s[i] = f2bf(r < 64 ? aw2[r * 64 + c] : cw2[(r - 64) * 64 + c]); return; }
    i -= 8192;
    if (i < 13312) { int r = i >> 6, c = i & 63;
        w3s[i] = f2bf(r < 200 ? aw3[r * 64 + c] : 0.f); return; }
    i -= 13312;
    if (i < 128) { b1c[i] = i < 64 ? ab1[i] : cb1[i - 64]; return; }
    i -= 128;
    if (i < 128) { b2c[i] = i < 64 ? ab2[i] : cb2[i - 64]; return; }
    i -= 128;
    if (i < 208) { b3s[i] = i < 200 ? ab3[i] : 0.f; return; }
}

__global__ void f2b_kernel(const float* __restrict__ s, unsigned short* __restrict__ d, int n) {
    int i = (blockIdx.x * 256 + threadIdx.x) * 4;
    if (i < n) {
        float4 v = *(const float4*)(s + i);
        ushort4 o;
        o.x = f2bf(v.x); o.y = f2bf(v.y); o.z = f2bf(v.z); o.w = f2bf(v.w);
        *(ushort4*)(d + i) = o;
    }
}

__global__ void zero_kernel(float4* __restrict__ p) {
    p[(size_t)blockIdx.x * 256 + threadIdx.x] = make_float4(0.f, 0.f, 0.f, 0.f);
}

__global__ void copy_actions(const int* __restrict__ a, float* __restrict__ o, int n) {
    int i = blockIdx.x * 256 + threadIdx.x;
    if (i < n) o[i] = (float)a[i];
}

extern "C" void kernel_launch(void* const* d_in, const int* in_sizes, int n_in,
                              void* d_out, int out_size, void* d_ws, size_t ws_size,
                              hipStream_t stream)
{
    const float* images = (const float*)d_in[0];
    const int*   actions = (const int*)d_in[1];
    const float* enc_w1 = (const float*)d_in[2];
    const float* enc_b1 = (const float*)d_in[3];
    const float* enc_w2 = (const float*)d_in[4];
    const float* enc_b2 = (const float*)d_in[5];
    const float* gru_wih = (const float*)d_in[6];
    const float* gru_bih = (const float*)d_in[7];
    const float* gru_whh = (const float*)d_in[8];
    const float* gru_bhh = (const float*)d_in[9];
    const float* act_w1 = (const float*)d_in[10];
    const float* act_b1 = (const float*)d_in[11];
    const float* act_w2 = (const float*)d_in[12];
    const float* act_b2 = (const float*)d_in[13];
    const float* act_w3 = (const float*)d_in[14];
    const float* act_b3 = (const float*)d_in[15];
    const float* cri_w1 = (const float*)d_in[16];
    const float* cri_b1 = (const float*)d_in[17];
    const float* cri_w2 = (const float*)d_in[18];
    const float* cri_b2 = (const float*)d_in[19];
    const float* cri_w3 = (const float*)d_in[20];
    const float* cri_b3 = (const float*)d_in[21];

    char* ws = (char*)d_ws;
    // region 0 (64 MiB): images bf16 (67,108,864 B), later overwritten by xg fp16 (50,331,648 B)
    unsigned short* imgb = (unsigned short*)ws;
    __half*         xg   = (__half*)ws;
    unsigned short* hbA  = (unsigned short*)(ws + 67108864);
    unsigned short* hbB  = hbA + (size_t)BB * HH;
    unsigned short* w1b  = hbB + (size_t)BB * HH;
    unsigned short* w2b  = w1b + 512 * DIMG;
    unsigned short* wihb = w2b + 512 * 512;
    unsigned short* whhb = wihb + 3 * HH * HH;
    unsigned short* w1c  = whhb + 3 * HH * HH;        // [128,512]
    unsigned short* w2s  = w1c + 128 * 512;           // [128,64]
    unsigned short* w3s  = w2s + 128 * 64;            // [208,64]
    float*          b1c  = (float*)(w3s + 208 * 64);
    float*          b2c  = b1c + 128;
    float*          b3s  = b2c + 128;

    float* out_act = (float*)d_out;
    float* out_lp  = out_act + (size_t)BB * TT;
    float* out_ent = out_lp  + (size_t)BB * TT;
    float* out_v   = out_ent + (size_t)BB * TT;

    dim3 blk(256);

    f2b_kernel<<<(BB * DIMG / 4 + 255) / 256, blk, 0, stream>>>(images, imgb, BB * DIMG);
    f2b_kernel<<<(512 * DIMG / 4 + 255) / 256, blk, 0, stream>>>(enc_w1, w1b, 512 * DIMG);
    f2b_kernel<<<(512 * 512 / 4 + 255) / 256, blk, 0, stream>>>(enc_w2, w2b, 512 * 512);
    f2b_kernel<<<(3 * HH * HH / 4 + 255) / 256, blk, 0, stream>>>(gru_wih, wihb, 3 * HH * HH);
    f2b_kernel<<<(3 * HH * HH / 4 + 255) / 256, blk, 0, stream>>>(gru_whh, whhb, 3 * HH * HH);
    prep_heads<<<(87504 + 255) / 256, blk, 0, stream>>>(
        act_w1, cri_w1, act_w2, cri_w2, act_w3,
        act_b1, cri_b1, act_b2, cri_b2, act_b3,
        w1c, w2s, w3s, b1c, b2c, b3s);

    // encoder + input-gate GEMMs; xg stored fp16 (written after imgb's last read)
    gemm_bt_mfma<1, 1><<<dim3(BB / 128, 4), blk, 0, stream>>>(imgb, w1b, enc_b1, hbA, BB, 512, DIMG);
    gemm_bt_mfma<0, 1><<<dim3(BB / 128, 4), blk, 0, stream>>>(hbA, w2b, enc_b2, hbB, BB, 512, HH);
    gemm_bt_mfma<0, 2><<<dim3(BB / 128, 12), blk, 0, stream>>>(hbB, wihb, gru_bih, xg, BB, 1536, HH);

    zero_kernel<<<4096, blk, 0, stream>>>((float4*)hbA);   // h0 = 0
    copy_actions<<<(BB * TT + 255) / 256, blk, 0, stream>>>(actions, out_act, BB * TT);

    for (int t = 0; t < TT; ++t) {
        const unsigned short* hin = (t & 1) ? hbB : hbA;
        unsigned short*      hout = (t & 1) ? hbA : hbB;
        step_fused<<<1536, blk, 0, stream>>>(hin, hout, whhb, gru_bhh, xg,
            w1c, w2s, w3s, b1c, b2c, b3s, cri_w3, cri_b3, actions,
            out_lp, out_ent, out_v, t - 1);
    }
    heads_tail<<<512, blk, 0, stream>>>(hbA, w1c, w2s, w3s, b1c, b2c, b3s,
        cri_w3, cri_b3, actions, out_lp, out_ent, out_v, TT - 1);
}